// Round 5
// baseline (1714.830 us; speedup 1.0000x reference)
//
#include <hip/hip_runtime.h>
#include <stdint.h>

// ---------------------------------------------------------------------------
// TransformerBlock fused pipeline for MI355X (gfx950), bf16 MFMA path.
//   B=1024, P=9, D=2700, DFF=512.  M = B*P = 9216 rows.
//   N packed = 8192 (q:0..2699, k:2700..5399, v:5400..8099, pad to 8192)
//   K1 padded 2700->2752 (x @ W), K2 = 1024 exactly ([H1|H2] @ [[WC1],[WC2]])
// Round 7: counted-vmcnt pipelined GEMM with SPILL-PROOF geometry.
//   BM=256 x BN=128, BK=64, 8 waves (4Mx2N -> 64x64/wave, acc[4][4]=64 regs —
//   identical per-thread register content to the verified 723-us gemm_fused).
//   Triple-buffered LDS (3 x 48 KB = 144 KB), loads issued 2 tiles ahead,
//   vmcnt(6) at tile start (never 0 in steady state), setprio around MFMA,
//   sched_barrier after lgkmcnt (rule: compiler hoists MFMA past asm waits).
//   No __launch_bounds__ (the (512,N) variants coincided with the rounds-3/5
//   128-VGPR/scratch pathology). Biases preloaded + fenced so vmcnt counts
//   stay exact. cvt/attn_ln unchanged from the 1079-us round-6 kernel.
// ---------------------------------------------------------------------------

#define MROWS  9216
#define NCOLS  8192
#define KP1    2752
#define KP2    1024
#define DMODEL 2700

typedef __bf16 bf16x8 __attribute__((ext_vector_type(8)));
typedef float  f32x4  __attribute__((ext_vector_type(4)));

__device__ __forceinline__ float b2f(unsigned short u) {
  union { unsigned int u; float f; } v; v.u = ((unsigned int)u) << 16; return v.f;
}
__device__ __forceinline__ unsigned short f2b(float f) {
  union { float f; unsigned int u; } v; v.f = f;
  unsigned int r = v.u + 0x7FFFu + ((v.u >> 16) & 1u);   // RNE
  return (unsigned short)(r >> 16);
}

// async global->LDS, 16B per lane (wave-uniform base + lane*16)
__device__ __forceinline__ void gl2lds16(const void* g, void* l) {
  __builtin_amdgcn_global_load_lds(
      (const __attribute__((address_space(1))) void*)g,
      (__attribute__((address_space(3))) void*)l, 16, 0, 0);
}

#define BAR() __builtin_amdgcn_s_barrier()

// ---------------------------------------------------------------------------
// conversion / packing kernels (round-6, harness-verified)
// ---------------------------------------------------------------------------

__global__ void cvt_x(const float* __restrict__ src, unsigned short* __restrict__ dst) {
  int t = blockIdx.x * 256 + threadIdx.x;          // grid: 9216*344/256 = 12384
  int r = t / 344;
  int c8 = (t - r * 344) * 8;
  const float* row = src + (size_t)r * DMODEL;
  unsigned int w[4];
  if (c8 + 8 <= DMODEL) {
    float4 a = *(const float4*)(row + c8);
    float4 b = *(const float4*)(row + c8 + 4);
    w[0] = (unsigned int)f2b(a.x) | ((unsigned int)f2b(a.y) << 16);
    w[1] = (unsigned int)f2b(a.z) | ((unsigned int)f2b(a.w) << 16);
    w[2] = (unsigned int)f2b(b.x) | ((unsigned int)f2b(b.y) << 16);
    w[3] = (unsigned int)f2b(b.z) | ((unsigned int)f2b(b.w) << 16);
  } else {
#pragma unroll
    for (int h = 0; h < 4; h++) {
      int c0 = c8 + 2 * h, c1 = c8 + 2 * h + 1;
      unsigned int lo = (c0 < DMODEL) ? f2b(row[c0]) : 0u;
      unsigned int hi = (c1 < DMODEL) ? f2b(row[c1]) : 0u;
      w[h] = lo | (hi << 16);
    }
  }
  *(uint4*)(dst + (size_t)t * 8) = make_uint4(w[0], w[1], w[2], w[3]);
}

__global__ void cvt_h(const float* __restrict__ H1, const float* __restrict__ H2,
                      unsigned short* __restrict__ dst) {
  int t = blockIdx.x * 256 + threadIdx.x;          // grid: 9216*128/256 = 4608
  int r = t >> 7, c8 = (t & 127) * 8;
  const float* row = (c8 < 512) ? (H1 + (size_t)r * 512 + c8)
                                : (H2 + (size_t)r * 512 + (c8 - 512));
  float4 a = *(const float4*)(row);
  float4 b = *(const float4*)(row + 4);
  unsigned int w0 = (unsigned int)f2b(a.x) | ((unsigned int)f2b(a.y) << 16);
  unsigned int w1 = (unsigned int)f2b(a.z) | ((unsigned int)f2b(a.w) << 16);
  unsigned int w2 = (unsigned int)f2b(b.x) | ((unsigned int)f2b(b.y) << 16);
  unsigned int w3 = (unsigned int)f2b(b.z) | ((unsigned int)f2b(b.w) << 16);
  *(uint4*)(dst + (size_t)t * 8) = make_uint4(w0, w1, w2, w3);
}

__global__ void cvt_wqkv(const float* __restrict__ Wq, const float* __restrict__ Wk,
                         const float* __restrict__ Wv, unsigned short* __restrict__ Wt) {
  __shared__ float tile[64][65];
  const int k0 = blockIdx.x * 64;
  const int n0 = blockIdx.y * 64;
  const int tx = threadIdx.x & 63, tg = threadIdx.x >> 6;
  const int nn_r = n0 + tx;
  int sec = (nn_r >= 5400) ? 2 : ((nn_r >= 2700) ? 1 : 0);
  int d = nn_r - sec * DMODEL;
  const float* W = (sec == 0) ? Wq : ((sec == 1) ? Wk : Wv);
  bool cvalid = (nn_r < 3 * DMODEL);
#pragma unroll
  for (int rr = 0; rr < 16; rr++) {
    int kk = k0 + tg * 16 + rr;
    float v = 0.f;
    if (kk < DMODEL && cvalid) v = W[(size_t)kk * DMODEL + d];
    tile[tg * 16 + rr][tx] = v;
  }
  __syncthreads();
#pragma unroll
  for (int rr = 0; rr < 16; rr++) {
    int nn = n0 + tg * 16 + rr;
    Wt[(size_t)nn * KP1 + k0 + tx] = f2b(tile[tx][tg * 16 + rr]);
  }
}

__global__ void cvt_wc(const float* __restrict__ C1q, const float* __restrict__ C1k,
                       const float* __restrict__ C1v, const float* __restrict__ C2q,
                       const float* __restrict__ C2k, const float* __restrict__ C2v,
                       unsigned short* __restrict__ Wt) {
  __shared__ float tile[64][65];
  const int k0 = blockIdx.x * 64;
  const int n0 = blockIdx.y * 64;
  const int tx = threadIdx.x & 63, tg = threadIdx.x >> 6;
  const int nn_r = n0 + tx;
  int sec = (nn_r >= 5400) ? 2 : ((nn_r >= 2700) ? 1 : 0);
  int d = nn_r - sec * DMODEL;
  bool cvalid = (nn_r < 3 * DMODEL);
  const float* W1 = (sec == 0) ? C1q : ((sec == 1) ? C1k : C1v);
  const float* W2 = (sec == 0) ? C2q : ((sec == 1) ? C2k : C2v);
#pragma unroll
  for (int rr = 0; rr < 16; rr++) {
    int kk = k0 + tg * 16 + rr;
    const float* W = (kk < 512) ? W1 : W2;
    int kr = (kk < 512) ? kk : (kk - 512);
    float v = cvalid ? W[(size_t)kr * DMODEL + d] : 0.f;
    tile[tg * 16 + rr][tx] = v;
  }
  __syncthreads();
#pragma unroll
  for (int rr = 0; rr < 16; rr++) {
    int nn = n0 + tg * 16 + rr;
    Wt[(size_t)nn * KP2 + k0 + tx] = f2b(tile[tx][tg * 16 + rr]);
  }
}

// ---------------------------------------------------------------------------
// Counted-vmcnt triple-buffer GEMM pipe.
//   Per tile (BK=64): {vmcnt(6); BAR; issue 3 loads of t+2; ds_read c0;
//   lgkmcnt(0)+sched_barrier; setprio(1) 16 MFMA; issue 3 loads; ds_read c1;
//   16 MFMA; BAR}.  Loads run 2 tiles ahead (~600 cy cover, 1 block/CU).
//   Staging into buffer X is only issued after a barrier that postdates all
//   reads of X (readers of tile t-1 finish before tile-t's post-vmcnt BAR).
//   A: 256 rows (4 loads/thread), B: 128 rows (2 loads/thread); XOR-swizzled
//   16B k-blocks exactly as the verified gemm_fused layout.
// ---------------------------------------------------------------------------
template<int NT, int KS>
__device__ __forceinline__ void pipe_gemm(
    unsigned short (&lds)[3][24576],
    const unsigned short* Aptr,   // + (m0+sr)*KS + skb  (per-thread)
    const unsigned short* Bptr,   // + (n0+sr)*KS + skb  (per-thread)
    f32x4 (&acc)[4][4],
    int tid, int wm, int wn, int lm, int lq, int l7)
{
  auto stA = [&](int buf, int u, int t) {
    gl2lds16(Aptr + (size_t)u * 64 * KS + (size_t)t * 64,
             &lds[buf][(u * 512 + tid) * 8]);
  };
  auto stB = [&](int buf, int u, int t) {
    gl2lds16(Bptr + (size_t)u * 64 * KS + (size_t)t * 64,
             &lds[buf][16384 + (u * 512 + tid) * 8]);
  };
  bf16x8 af[4], bfr[4];
  auto frags = [&](int buf, int c) {
    const int kx = ((c * 4 + lq) ^ l7) * 8;
#pragma unroll
    for (int i = 0; i < 4; i++) {
      af[i]  = *(const bf16x8*)&lds[buf][(wm + i * 16 + lm) * 64 + kx];
      bfr[i] = *(const bf16x8*)&lds[buf][16384 + (wn + i * 16 + lm) * 64 + kx];
    }
  };
  auto mfmas = [&]() {
    asm volatile("s_waitcnt lgkmcnt(0)" ::: "memory");
    __builtin_amdgcn_sched_barrier(0);
    __builtin_amdgcn_s_setprio(1);
#pragma unroll
    for (int mt = 0; mt < 4; mt++)
#pragma unroll
      for (int nt = 0; nt < 4; nt++)
        acc[mt][nt] = __builtin_amdgcn_mfma_f32_16x16x32_bf16(
            af[mt], bfr[nt], acc[mt][nt], 0, 0, 0);
    __builtin_amdgcn_s_setprio(0);
  };

  // prologue: tiles 0 -> buf0, 1 -> buf1 (12 loads in flight)
  stA(0, 0, 0); stA(0, 1, 0); stB(0, 0, 0);
  stA(0, 2, 0); stA(0, 3, 0); stB(0, 1, 0);
  stA(1, 0, 1); stA(1, 1, 1); stB(1, 0, 1);
  stA(1, 2, 1); stA(1, 3, 1); stB(1, 1, 1);

  int buf = 0, bpre = 2;
#pragma unroll 1
  for (int t = 0; t < NT; ++t) {
    if (t + 1 < NT) asm volatile("s_waitcnt vmcnt(6)" ::: "memory");  // tile t landed
    else            asm volatile("s_waitcnt vmcnt(0)" ::: "memory");
    BAR();                                        // all waves' tile-t data in LDS
    const bool pre = (t + 2 < NT);
    if (pre) { stA(bpre, 0, t + 2); stA(bpre, 1, t + 2); stB(bpre, 0, t + 2); }
    frags(buf, 0);
    mfmas();
    if (pre) { stA(bpre, 2, t + 2); stA(bpre, 3, t + 2); stB(bpre, 1, t + 2); }
    frags(buf, 1);
    mfmas();
    BAR();                                        // close readers of buf
    buf  = (buf  == 2) ? 0 : buf  + 1;
    bpre = (bpre == 2) ? 0 : bpre + 1;
  }
}

// ---------------------------------------------------------------------------
// Fused double GEMM, pipelined:  MQ = bf16((Xb@Wt^T + b) * (Hb@WCt^T + bc))
//   grid 2304 = 36 m-tiles x 64 n-tiles; XCD-chunked swizzle, n fastest
//   (A-panel L2 reuse across 64 consecutive same-XCD blocks).
// ---------------------------------------------------------------------------
__global__ void gemm_pipe(
    const unsigned short* __restrict__ Xb,
    const unsigned short* __restrict__ Wt,
    const unsigned short* __restrict__ Hb,
    const unsigned short* __restrict__ WCt,
    unsigned short* __restrict__ MQ,
    const float* __restrict__ bq_, const float* __restrict__ bk_, const float* __restrict__ bv_,
    const float* __restrict__ b1q, const float* __restrict__ b1k, const float* __restrict__ b1v,
    const float* __restrict__ b2q, const float* __restrict__ b2k, const float* __restrict__ b2v)
{
  __shared__ __attribute__((aligned(16))) unsigned short lds[3][24576];  // 144 KiB
  const int tid = threadIdx.x;
  const int wave = tid >> 6, lane = tid & 63;
  const int wm = (wave >> 1) * 64, wn = (wave & 1) * 64;   // 4M x 2N waves
  const int lm = lane & 15, lq = lane >> 4, l7 = lane & 7;
  // bijective XCD-chunked swizzle: 2304 % 8 == 0
  const int wg = blockIdx.x;
  const int swz = (wg & 7) * 288 + (wg >> 3);
  const int m0 = (swz >> 6) * 256;       // swz/64 in [0,36)
  const int n0 = (swz & 63) * 128;       // n fastest -> A-panel reuse
  const int sr = tid >> 3;
  const int skb = ((tid & 7) ^ (sr & 7)) * 8;

  // ---- preload biases (before pipeline so vmcnt counts stay exact) ----
  float bmodv[4], bmainv[4];
#pragma unroll
  for (int nt = 0; nt < 4; nt++) {
    int gc = n0 + wn + nt * 16 + lm;
    float vm = 0.f, vb = 0.f;
    if (gc < 3 * DMODEL) {
      int sec = (gc >= 5400) ? 2 : ((gc >= 2700) ? 1 : 0);
      int d = gc - sec * DMODEL;
      const float* u1 = (sec == 0) ? b1q : ((sec == 1) ? b1k : b1v);
      const float* u2 = (sec == 0) ? b2q : ((sec == 1) ? b2k : b2v);
      const float* bm = (sec == 0) ? bq_ : ((sec == 1) ? bk_ : bv_);
      vm = u1[d] + u2[d];
      vb = bm[d];
    }
    bmodv[nt] = vm; bmainv[nt] = vb;
  }
  asm volatile("" :: "v"(bmodv[0]), "v"(bmodv[1]), "v"(bmodv[2]), "v"(bmodv[3]),
                     "v"(bmainv[0]), "v"(bmainv[1]), "v"(bmainv[2]), "v"(bmainv[3]));
  asm volatile("s_waitcnt vmcnt(0) lgkmcnt(0)" ::: "memory");

  f32x4 acc[4][4];
#pragma unroll
  for (int i = 0; i < 4; i++)
#pragma unroll
    for (int j = 0; j < 4; j++) acc[i][j] = (f32x4){0.f, 0.f, 0.f, 0.f};

  // ---- phase A: modulation GEMM, K = 1024 (16 tiles) ----
  {
    const unsigned short* Ap = Hb  + (size_t)(m0 + sr) * KP2 + skb;
    const unsigned short* Bp = WCt + (size_t)(n0 + sr) * KP2 + skb;
    pipe_gemm<16, KP2>(lds, Ap, Bp, acc, tid, wm, wn, lm, lq, l7);
  }

  // save modulation (+ bias) packed bf16; reset acc  (register-only)
  unsigned int modp[4][4][2];
#pragma unroll
  for (int nt = 0; nt < 4; nt++) {
#pragma unroll
    for (int mt = 0; mt < 4; mt++) {
#pragma unroll
      for (int h = 0; h < 2; h++) {
        unsigned int lo = f2b(acc[mt][nt][2 * h] + bmodv[nt]);
        unsigned int hi = f2b(acc[mt][nt][2 * h + 1] + bmodv[nt]);
        modp[mt][nt][h] = lo | (hi << 16);
      }
    }
  }
#pragma unroll
  for (int i = 0; i < 4; i++)
#pragma unroll
    for (int j = 0; j < 4; j++) acc[i][j] = (f32x4){0.f, 0.f, 0.f, 0.f};

  // ---- phase B: main GEMM, K = 2752 (43 tiles) ----
  {
    const unsigned short* Ap = Xb + (size_t)(m0 + sr) * KP1 + skb;
    const unsigned short* Bp = Wt + (size_t)(n0 + sr) * KP1 + skb;
    pipe_gemm<43, KP1>(lds, Ap, Bp, acc, tid, wm, wn, lm, lq, l7);
  }

  // ---- epilogue: qkv = (main + b) * mod  (verified store pattern) ----
#pragma unroll
  for (int nt = 0; nt < 4; nt++) {
    int gc = n0 + wn + nt * 16 + lm;
#pragma unroll
    for (int mt = 0; mt < 4; mt++) {
      int grb = m0 + wm + mt * 16 + lq * 4;   // C/D: col=lane&15, row=quad*4+i
#pragma unroll
      for (int i = 0; i < 4; i++) {
        float mod = b2f((unsigned short)(modp[mt][nt][i >> 1] >> ((i & 1) * 16)));
        MQ[(size_t)(grb + i) * NCOLS + gc] = f2b((acc[mt][nt][i] + bmainv[nt]) * mod);
      }
    }
  }
}

// ---------------------------------------------------------------------------
// Fused attention (9x9) + softmax + residual + LayerNorm (unchanged, verified)
// ---------------------------------------------------------------------------
__global__ __launch_bounds__(256, 2) void attn_ln(
    const unsigned short* __restrict__ qkv,  // [9216][8192] bf16 (q|k|v packed)
    const float* __restrict__ x,             // [9216][2700] fp32
    const float* __restrict__ gamma, const float* __restrict__ beta,
    float* __restrict__ out)                 // [9216][2700] fp32
{
  __shared__ float part[4][81];
  __shared__ float sc[81];
  __shared__ float redS[4][9], redQ[4][9];
  __shared__ float muL[9], rsL[9];

  const int b = blockIdx.x;
  const int tid = threadIdx.x, wave = tid >> 6, lane = tid & 63;
  const unsigned short* qb = qkv + (size_t)b * 9 * NCOLS;

  // ---- phase 1: scores S[i][j] = q_i . k_j via 16x16x32 MFMA, K-split ----
  {
    const int l15 = lane & 15, lq8 = (lane >> 4) * 8;
    const int rA = (l15 < 9) ? l15 : 8;
    const unsigned short* qrow = qb + (size_t)rA * NCOLS;
    const unsigned short* krow = qb + (size_t)rA * NCOLS + DMODEL;
    f32x4 accS = (f32x4){0.f, 0.f, 0.f, 0.f};
    for (int s = wave; s < 85; s += 4) {
      int k0 = s * 32 + lq8;
      union { uint2 u[2]; unsigned int w[4]; bf16x8 v; } au, bu;
      au.u[0] = *(const uint2*)(qrow + k0);
      au.u[1] = *(const uint2*)(qrow + k0 + 4);
      bu.u[0] = *(const uint2*)(krow + k0);
      bu.u[1] = *(const uint2*)(krow + k0 + 4);
      if (s == 84) {
#pragma unroll
        for (int wd = 0; wd < 4; wd++)
          if (k0 + 2 * wd >= DMODEL) { au.w[wd] = 0u; bu.w[wd] = 0u; }
      }
      accS = __builtin_amdgcn_mfma_f32_16x16x32_bf16(au.v, bu.v, accS, 0, 0, 0);
    }
#pragma unroll
    for (int i = 0; i < 4; i++) {
      int row = (lane >> 4) * 4 + i, col = l15;
      if (row < 9 && col < 9) part[wave][row * 9 + col] = accS[i];
    }
  }
  __syncthreads();

  if (tid < 81)
    sc[tid] = (part[0][tid] + part[1][tid] + part[2][tid] + part[3][tid])
              * 0.019245008972987526f;
  __syncthreads();

  if (tid < 9) {
    float mx = -1e30f;
#pragma unroll
    for (int j = 0; j < 9; j++) mx = fmaxf(mx, sc[tid * 9 + j]);
    float e[9], sum = 0.f;
#pragma unroll
    for (int j = 0; j < 9; j++) { e[j] = __expf(sc[tid * 9 + j] - mx); sum += e[j]; }
    float inv = 1.f / sum;
#pragma unroll
    for (int j = 0; j < 9; j++) sc[tid * 9 + j] = e[j] * inv;
  }
  __syncthreads();

  float sum[9], sq[9];
#pragma unroll
  for (int i = 0; i < 9; i++) { sum[i] = 0.f; sq[i] = 0.f; }
  unsigned int pv[9][3][2];
#pragma unroll
  for (int c = 0; c < 3; c++) {
    int e = tid + c * 256;
    if (e < 675) {
      float4 t4[9];
#pragma unroll
      for (int i = 0; i < 9; i++)
        t4[i] = ((const float4*)(x + (size_t)(b * 9 + i) * DMODEL))[e];
#pragma unroll
      for (int j = 0; j < 9; j++) {
        ushort4 vv = ((const ushort4*)(qb + (size_t)j * NCOLS + 5400))[e];
        float v0 = b2f(vv.x), v1 = b2f(vv.y), v2 = b2f(vv.z), v3 = b2f(vv.w);
#pragma unroll
        for (int i = 0; i < 9; i++) {
          float p = sc[i * 9 + j];
          t4[i].x += p * v0; t4[i].y += p * v1;
          t4[i].z += p * v2; t4[i].w += p * v3;
        }
      }
#pragma unroll
      for (int i = 0; i < 9; i++) {
        sum[i] += t4[i].x + t4[i].y + t4[i].z + t4[i].w;
        sq[i]  += t4[i].x * t4[i].x + t4[i].y * t4[i].y
                + t4[i].z * t4[i].z + t4[i].w * t4[i].w;
        pv[i][c][0] = (unsigned int)f2b(t4[i].x) | ((unsigned int)f2b(t4[i].y) << 16);
        pv[i][c][1] = (unsigned int)f2b(t4[i].z) | ((unsigned int)f2b(t4[i].w) << 16);
      }
    }
  }

#pragma unroll
  for (int i = 0; i < 9; i++) {
    float s = sum[i], q = sq[i];
#pragma unroll
    for (int off = 32; off > 0; off >>= 1) {
      s += __shfl_down(s, off, 64);
      q += __shfl_down(q, off, 64);
    }
    if (lane == 0) { redS[wave][i] = s; redQ[wave][i] = q; }
  }
  __syncthreads();
  if (tid < 9) {
    float ts = redS[0][tid] + redS[1][tid] + redS[2][tid] + redS[3][tid];
    float tq = redQ[0][tid] + redQ[1][tid] + redQ[2][tid] + redQ[3][tid];
    float mu = ts * (1.f / 2700.f);
    muL[tid] = mu;
    rsL[tid] = rsqrtf(tq * (1.f / 2700.f) - mu * mu + 1e-5f);
  }
  __syncthreads();

#pragma unroll
  for (int c = 0; c < 3; c++) {
    int e = tid + c * 256;
    if (e < 675) {
      float4 g = ((const float4*)gamma)[e];
      float4 bb = ((const float4*)beta)[e];
#pragma unroll
      for (int i = 0; i < 9; i++) {
        float m = muL[i], r = rsL[i];
        float t0 = b2f((unsigned short)(pv[i][c][0] & 0xFFFF));
        float t1 = b2f((unsigned short)(pv[i][c][0] >> 16));
        float t2 = b2f((unsigned short)(pv[i][c][1] & 0xFFFF));
        float t3 = b2f((unsigned short)(pv[i][c][1] >> 16));
        float4 o;
        o.x = (t0 - m) * r * g.x + bb.x;
        o.y = (t1 - m) * r * g.y + bb.y;
        o.z = (t2 - m) * r * g.z + bb.z;
        o.w = (t3 - m) * r * g.w + bb.w;
        ((float4*)(out + (size_t)(b * 9 + i) * DMODEL))[e] = o;
      }
    }
  }
}

// ---------------------------------------------------------------------------
extern "C" void kernel_launch(void* const* d_in, const int* in_sizes, int n_in,
                              void* d_out, int out_size, void* d_ws, size_t ws_size,
                              hipStream_t stream) {
  const float* state = (const float*)d_in[0];
  const float* H1    = (const float*)d_in[1];
  const float* H2    = (const float*)d_in[2];
  const float* Wq    = (const float*)d_in[3];
  const float* bq    = (const float*)d_in[4];
  const float* Wk    = (const float*)d_in[5];
  const float* bk    = (const float*)d_in[6];
  const float* Wv    = (const float*)d_in[7];
  const float* bv    = (const float*)d_in[8];
  const float* WC1q  = (const float*)d_in[9];
  const float* bC1q  = (const float*)d_in[10];
  const float* WC1k  = (const float*)d_in[11];
  const float* bC1k  = (const float*)d_in[12];
  const float* WC1v  = (const float*)d_in[13];
  const float* bC1v  = (const float*)d_in[14];
  const float* WC2q  = (const float*)d_in[15];
  const float* bC2q  = (const float*)d_in[16];
  const float* WC2k  = (const float*)d_in[17];
  const float* bC2k  = (const float*)d_in[18];
  const float* WC2v  = (const float*)d_in[19];
  const float* bC2v  = (const float*)d_in[20];
  const float* gamma = (const float*)d_in[21];
  const float* beta  = (const float*)d_in[22];
  float* out = (float*)d_out;

  // workspace layout (256B aligned), total 282,460,160 B
  char* ws = (char*)d_ws;
  unsigned short* Xb  = (unsigned short*)(ws + 0);            // 9216*2752*2
  unsigned short* Wt  = (unsigned short*)(ws + 50724864);     // 8192*2752*2
  unsigned short* Hb  = (unsigned short*)(ws + 95813632);     // 9216*1024*2
  unsigned short* WCt = (unsigned short*)(ws + 114688000);    // 8192*1024*2
  unsigned short* MQ  = (unsigned short*)(ws + 131465216);    // 9216*8192*2

  // 1) convert / pack (vectorized / full-line versions)
  cvt_x<<<dim3(12384), dim3(256), 0, stream>>>(state, Xb);
  cvt_wqkv<<<dim3(43, 128), dim3(256), 0, stream>>>(Wq, Wk, Wv, Wt);
  cvt_h<<<dim3(4608), dim3(256), 0, stream>>>(H1, H2, Hb);
  cvt_wc<<<dim3(16, 128), dim3(256), 0, stream>>>(WC1q, WC1k, WC1v,
                                                  WC2q, WC2k, WC2v, WCt);

  // 2) fused double GEMM (pipelined): MQ = (Xb@Wt^T + b) * (Hb@WCt^T + bc)
  gemm_pipe<<<dim3(2304), dim3(512), 0, stream>>>(
      Xb, Wt, Hb, WCt, MQ, bq, bk, bv, bC1q, bC1k, bC1v, bC2q, bC2k, bC2v);

  // 3) attention + softmax + residual + layernorm
  attn_ln<<<dim3(1024), dim3(256), 0, stream>>>(MQ, state, gamma, beta, out);
}